// Round 7
// baseline (348.355 us; speedup 1.0000x reference)
//
#include <hip/hip_runtime.h>
#include <hip/hip_bf16.h>

#define VNUM 6890
#define KJ 24
#define NBETA 10
#define NPOSE 207
#define KPAD 224        // NPOSE padded to 7*32
#define BATCH 1024
#define N3 20670        // VNUM*3
#define PDROWS 20736    // 324*64 rows in pdT (48-tile reads up to 20687, 64-tile writes to 20735)

// d_out element offsets (f32 elements)
#define OUT_V  0
#define OUT_JT 21166080
#define OUT_J  21239808
#define OUT_RM 21313536

// ws offsets (float units)
#define WS_JVJS 0                 // 792 floats
#define WS_A    792               // 294912 floats -> ends 295704
#define WS_PFB  295704            // ushort[1024*224]   = 114688 floats -> ends 410392
#define WS_PDT  410392            // ushort[20736*224]  = 2322432 floats -> ends 2732824 (~10.9 MB)

typedef unsigned short ushort;
typedef __attribute__((ext_vector_type(8))) short short8v;
typedef __attribute__((ext_vector_type(4))) float floatx4;

__device__ __forceinline__ ushort f2bfu(float x) {
  __hip_bfloat16 h = __float2bfloat16(x);
  union { __hip_bfloat16 h; ushort u; } cv; cv.h = h; return cv.u;
}

// ---------------------------------------------------------------------------
// Kernel 0: JvJs accumulation (4 V-chunks, atomicAdd combine)
// ---------------------------------------------------------------------------
__global__ __launch_bounds__(256) void jreg_kernel(
    const float* __restrict__ Jr, const float* __restrict__ vt,
    const float* __restrict__ sd, float* __restrict__ JvJs) {
  const int j = blockIdx.x;
  const int chunk = blockIdx.y;
  const int t = threadIdx.x;
  const int lane = t & 63, wid = t >> 6;
  const int vbeg = chunk * 1723;
  const int vend = (vbeg + 1723 < VNUM) ? vbeg + 1723 : VNUM;
  __shared__ float red[4][33];
  float acc[33];
#pragma unroll
  for (int q = 0; q < 33; q++) acc[q] = 0.0f;
  for (int v = vbeg + t; v < vend; v += 256) {
    float r = Jr[j * VNUM + v];
    const float* vtp = vt + v * 3;
    const float* sdp = sd + v * 30;
    acc[0] += r * vtp[0];
    acc[1] += r * vtp[1];
    acc[2] += r * vtp[2];
#pragma unroll
    for (int q = 0; q < 30; q++) acc[3 + q] += r * sdp[q];
  }
#pragma unroll
  for (int q = 0; q < 33; q++) {
    float x = acc[q];
    for (int off = 32; off > 0; off >>= 1) x += __shfl_down(x, off, 64);
    if (lane == 0) red[wid][q] = x;
  }
  __syncthreads();
  if (t < 33)
    atomicAdd(&JvJs[j * 33 + t], red[0][t] + red[1][t] + red[2][t] + red[3][t]);
}

// ---------------------------------------------------------------------------
// Kernel 1: per-batch: rodrigues, joints_t, pose_feature(bf16), chain, A
// ---------------------------------------------------------------------------
__global__ __launch_bounds__(64) void batch_prep(
    const float* __restrict__ body_pose, const float* __restrict__ betas,
    const float* __restrict__ global_orient, const float* __restrict__ JvJs,
    float* __restrict__ out_jt, float* __restrict__ out_j, float* __restrict__ out_rm,
    ushort* __restrict__ pfb, float* __restrict__ Amat) {
  const int b = blockIdx.x;
  const int t = threadIdx.x;
  __shared__ float R[24][9];
  __shared__ float jt[24][3];
  __shared__ float chR[24][9];
  __shared__ float cht[24][3];

  if (t < 24) {
    float ax, ay, az;
    if (t == 0) {
      ax = global_orient[b * 3 + 0];
      ay = global_orient[b * 3 + 1];
      az = global_orient[b * 3 + 2];
    } else {
      const float* p = body_pose + (size_t)b * 69 + (t - 1) * 3;
      ax = p[0]; ay = p[1]; az = p[2];
    }
    float px = ax + 1e-8f, py = ay + 1e-8f, pz = az + 1e-8f;
    float angle = sqrtf(px * px + py * py + pz * pz);
    float inv = 1.0f / angle;
    float rx = ax * inv, ry = ay * inv, rz = az * inv;
    float s = sinf(angle), c = cosf(angle);
    float cc = 1.0f - c;
    float m[9];
    m[0] = 1.0f - cc * (ry * ry + rz * rz);
    m[1] = -s * rz + cc * rx * ry;
    m[2] =  s * ry + cc * rx * rz;
    m[3] =  s * rz + cc * rx * ry;
    m[4] = 1.0f - cc * (rx * rx + rz * rz);
    m[5] = -s * rx + cc * ry * rz;
    m[6] = -s * ry + cc * rx * rz;
    m[7] =  s * rx + cc * ry * rz;
    m[8] = 1.0f - cc * (rx * rx + ry * ry);
#pragma unroll
    for (int e = 0; e < 9; e++) {
      R[t][e] = m[e];
      out_rm[(size_t)b * 216 + t * 9 + e] = m[e];
    }
  }
  for (int idx = t; idx < 72; idx += 64) {
    int j = idx / 3, c = idx % 3;
    const float* JJ = JvJs + j * 33;
    float s = JJ[c];
    const float* be = betas + (size_t)b * NBETA;
#pragma unroll
    for (int l = 0; l < NBETA; l++) s += be[l] * JJ[3 + c * 10 + l];
    jt[j][c] = s;
    out_jt[(size_t)b * 72 + idx] = s;
  }
  __syncthreads();
  for (int mI = t; mI < KPAD; mI += 64) {
    float val = 0.0f;
    if (mI < NPOSE) {
      int k = 1 + mI / 9, e = mI % 9;
      val = R[k][e] - ((e == 0 || e == 4 || e == 8) ? 1.0f : 0.0f);
    }
    pfb[(size_t)b * KPAD + mI] = f2bfu(val);
  }
  if (t == 0) {
    const int par[24] = {-1, 0, 0, 0, 1, 2, 3, 4, 5, 6, 7, 8, 9, 9, 9, 12, 13, 14, 16, 17, 18, 19, 20, 21};
#pragma unroll
    for (int e = 0; e < 9; e++) chR[0][e] = R[0][e];
    cht[0][0] = jt[0][0]; cht[0][1] = jt[0][1]; cht[0][2] = jt[0][2];
    for (int k = 1; k < 24; k++) {
      int p = par[k];
      float rel0 = jt[k][0] - jt[p][0];
      float rel1 = jt[k][1] - jt[p][1];
      float rel2 = jt[k][2] - jt[p][2];
#pragma unroll
      for (int i = 0; i < 3; i++) {
        float a0 = chR[p][i * 3 + 0], a1 = chR[p][i * 3 + 1], a2 = chR[p][i * 3 + 2];
        chR[k][i * 3 + 0] = a0 * R[k][0] + a1 * R[k][3] + a2 * R[k][6];
        chR[k][i * 3 + 1] = a0 * R[k][1] + a1 * R[k][4] + a2 * R[k][7];
        chR[k][i * 3 + 2] = a0 * R[k][2] + a1 * R[k][5] + a2 * R[k][8];
        cht[k][i] = a0 * rel0 + a1 * rel1 + a2 * rel2 + cht[p][i];
      }
    }
  }
  __syncthreads();
  if (t < 24) {
    int k = t;
#pragma unroll
    for (int i = 0; i < 3; i++) {
      float a0 = chR[k][i * 3], a1 = chR[k][i * 3 + 1], a2 = chR[k][i * 3 + 2];
      float tr = cht[k][i] - (a0 * jt[k][0] + a1 * jt[k][1] + a2 * jt[k][2]);
      Amat[(size_t)b * 288 + k * 12 + i * 4 + 0] = a0;
      Amat[(size_t)b * 288 + k * 12 + i * 4 + 1] = a1;
      Amat[(size_t)b * 288 + k * 12 + i * 4 + 2] = a2;
      Amat[(size_t)b * 288 + k * 12 + i * 4 + 3] = tr;
      out_j[(size_t)b * 72 + k * 3 + i] = cht[k][i];
    }
  }
}

// ---------------------------------------------------------------------------
// Kernel 2: pdT[n][k] = bf16(pd[k][n]); rows up to PDROWS zero-padded
// grid (324, 7), 256 threads
// ---------------------------------------------------------------------------
__global__ __launch_bounds__(256) void transpose_pd(
    const float* __restrict__ pd, ushort* __restrict__ pdT) {
  __shared__ float tile[32][65];
  const int t = threadIdx.x;
  const int n0 = blockIdx.x * 64;
  const int k0 = blockIdx.y * 32;
  const int c = t & 63;
  for (int r = t >> 6; r < 32; r += 4) {
    int k = k0 + r, n = n0 + c;
    tile[r][c] = (k < NPOSE && n < N3) ? pd[(size_t)k * N3 + n] : 0.0f;
  }
  __syncthreads();
  const int n = t >> 2;
  const int j0 = (t & 3) * 8;
  unsigned int outw[4];
#pragma unroll
  for (int jj = 0; jj < 4; jj++) {
    unsigned int lo = f2bfu(tile[j0 + jj * 2][n]);
    unsigned int hi = f2bfu(tile[j0 + jj * 2 + 1][n]);
    outw[jj] = lo | (hi << 16);
  }
  *(uint4*)&pdT[(size_t)(n0 + n) * KPAD + k0 + j0] =
      make_uint4(outw[0], outw[1], outw[2], outw[3]);
}

// ---------------------------------------------------------------------------
// Kernel 3 (FUSED): per block: 64 batches x 48 components (16 vertices).
// Phase 1: vposed = pf @ pdT via MFMA, fragments direct from global.
// Phase 2: + vt + sd@betas -> vp in LDS (f32). Never touches HBM.
// Phase 3: 4 rounds x 16 batches: T = w @ A[b] via MFMA, apply to vp, store.
// ---------------------------------------------------------------------------
__global__ __launch_bounds__(256) void fused_vb(
    const ushort* __restrict__ pfb, const ushort* __restrict__ pdT,
    const float* __restrict__ vt, const float* __restrict__ sd,
    const float* __restrict__ betas, const float* __restrict__ w,
    const float* __restrict__ Amat, float* __restrict__ out_v) {
  __shared__ __align__(16) ushort Ws[16 * 32];      // [v][k]   1 KB
  __shared__ __align__(16) ushort Agrp[16 * 288];   // [bl][n12][k24] 9 KB
  __shared__ __align__(16) float vp[64][52];        // 13.3 KB (52: 2-way-only banks)
  __shared__ __align__(16) float Ts[4][16 * 20];    // 5 KB
  __shared__ float vtS[48];
  __shared__ float sdS[48][10];
  __shared__ float betS[64][10];
  const int tid = threadIdx.x;
  const int lane = tid & 63, wv = tid >> 6;
  const int quad = lane >> 4, l15 = lane & 15;
  const int m0 = blockIdx.x * 64;   // batch base (x fastest -> pdT L2 reuse)
  const int n0 = blockIdx.y * 48;   // component base
  const int v0 = blockIdx.y * 16;   // vertex base

  // stage Ws (bf16 [16 v][32 k], zero-padded)
  for (int e = tid; e < 16 * 24; e += 256) {
    int v = e / 24, k = e % 24;
    int gv = v0 + v;
    Ws[v * 32 + k] = f2bfu((gv < VNUM) ? w[(size_t)gv * 24 + k] : 0.0f);
  }
  if (tid < 16 * 8) {
    int v = tid / 8, k = 24 + (tid % 8);
    Ws[v * 32 + k] = 0;
  }
  if (tid < 48) {
    int gn = n0 + tid;
    vtS[tid] = (gn < N3) ? vt[gn] : 0.0f;
  }
  for (int e = tid; e < 480; e += 256) {
    int n = e / 10, l = e % 10;
    int gn = n0 + n;
    sdS[n][l] = (gn < N3) ? sd[(size_t)gn * 10 + l] : 0.0f;
  }
  for (int e = tid; e < 640; e += 256) {
    int m = e / 10, l = e % 10;
    betS[m][l] = betas[(size_t)(m0 + m) * 10 + l];
  }

  // phase 1: MFMA over K=224, fragments straight from global
  floatx4 acc[3];
  const floatx4 zero = {0.0f, 0.0f, 0.0f, 0.0f};
#pragma unroll
  for (int ns = 0; ns < 3; ns++) acc[ns] = zero;
  const ushort* aptr = pfb + (size_t)(m0 + wv * 16 + l15) * KPAD;
#pragma unroll
  for (int kb = 0; kb < 7; kb++) {
    short8v av = *(const short8v*)&aptr[kb * 32 + quad * 8];
#pragma unroll
    for (int ns = 0; ns < 3; ns++) {
      short8v bv = *(const short8v*)&pdT[(size_t)(n0 + ns * 16 + l15) * KPAD + kb * 32 + quad * 8];
      acc[ns] = __builtin_amdgcn_mfma_f32_16x16x32_bf16(av, bv, acc[ns], 0, 0, 0);
    }
  }
  __syncthreads();   // staging (vtS/sdS/betS/Ws) visible

  // phase 2: epilogue, write vp
#pragma unroll
  for (int ns = 0; ns < 3; ns++) {
    int n = ns * 16 + l15;
    float vtv = vtS[n];
#pragma unroll
    for (int r = 0; r < 4; r++) {
      int m = wv * 16 + quad * 4 + r;
      float s = acc[ns][r] + vtv;
#pragma unroll
      for (int l = 0; l < 10; l++) s += betS[m][l] * sdS[n][l];
      vp[m][n] = s;
    }
  }
  __syncthreads();

  // phase 3: blend. 4 rounds of 16 batches; wave handles 4 batches/round.
  const int al = (lane < 48) ? lane : 0;
  const int appv = al / 3;
  const int appc = al - appv * 3;
  const bool store_ok = (lane < 48) && (n0 + lane < N3);
  float* myTs = &Ts[wv][0];
  short8v afw = *(const short8v*)&Ws[l15 * 32 + quad * 8];
  const bool bfrag_ok = (l15 < 12) && (quad < 3);

  for (int g = 0; g < 4; g++) {
    for (int e = tid; e < 16 * 288; e += 256) {
      int bl = e / 288, r = e - bl * 288;
      int n = r / 24, k = r - n * 24;
      Agrp[e] = f2bfu(Amat[(size_t)(m0 + g * 16 + bl) * 288 + k * 12 + n]);
    }
    __syncthreads();
#pragma unroll 1
    for (int bb = 0; bb < 4; bb++) {
      int bl = wv * 4 + bb;
      short8v bf = {0, 0, 0, 0, 0, 0, 0, 0};
      if (bfrag_ok) bf = *(const short8v*)&Agrp[bl * 288 + l15 * 24 + quad * 8];
      floatx4 t = zero;
      t = __builtin_amdgcn_mfma_f32_16x16x32_bf16(afw, bf, t, 0, 0, 0);
      int bloc = g * 16 + bl;
      float px = vp[bloc][appv * 3 + 0];
      float py = vp[bloc][appv * 3 + 1];
      float pz = vp[bloc][appv * 3 + 2];
#pragma unroll
      for (int r = 0; r < 4; r++) myTs[(quad * 4 + r) * 20 + l15] = t[r];
      __builtin_amdgcn_sched_barrier(0);
      __builtin_amdgcn_s_waitcnt(0xc07f);   // lgkmcnt(0): wave-private Ts done
      __builtin_amdgcn_sched_barrier(0);
      if (store_ok) {
        const float4 Tv = *(const float4*)&myTs[appv * 20 + appc * 4];
        out_v[(size_t)(m0 + bloc) * N3 + n0 + lane] =
            Tv.x * px + Tv.y * py + Tv.z * pz + Tv.w;
      }
      __builtin_amdgcn_sched_barrier(0);
    }
    __syncthreads();   // before next round overwrites Agrp
  }
}

extern "C" void kernel_launch(void* const* d_in, const int* in_sizes, int n_in,
                              void* d_out, int out_size, void* d_ws, size_t ws_size,
                              hipStream_t stream) {
  const float* body_pose     = (const float*)d_in[0];
  const float* betas         = (const float*)d_in[1];
  const float* global_orient = (const float*)d_in[2];
  const float* v_template    = (const float*)d_in[3];
  const float* shapedirs     = (const float*)d_in[4];
  const float* posedirs      = (const float*)d_in[5];
  const float* J_regressor   = (const float*)d_in[6];
  const float* lbs_weights   = (const float*)d_in[7];

  float* out = (float*)d_out;
  float* out_v  = out + OUT_V;
  float* out_jt = out + OUT_JT;
  float* out_j  = out + OUT_J;
  float* out_rm = out + OUT_RM;

  float* ws = (float*)d_ws;
  float* JvJs = ws + WS_JVJS;
  float* Amat = ws + WS_A;
  ushort* pfb = (ushort*)(ws + WS_PFB);
  ushort* pdT = (ushort*)(ws + WS_PDT);

  hipMemsetAsync(JvJs, 0, KJ * 33 * sizeof(float), stream);
  jreg_kernel<<<dim3(KJ, 4), 256, 0, stream>>>(J_regressor, v_template, shapedirs, JvJs);
  transpose_pd<<<dim3(324, 7), 256, 0, stream>>>(posedirs, pdT);
  batch_prep<<<BATCH, 64, 0, stream>>>(body_pose, betas, global_orient, JvJs,
                                       out_jt, out_j, out_rm, pfb, Amat);
  fused_vb<<<dim3(16, 431), 256, 0, stream>>>(pfb, pdT, v_template, shapedirs,
                                              betas, lbs_weights, Amat, out_v);
}